// Round 1
// baseline (1133.148 us; speedup 1.0000x reference)
//
#include <hip/hip_runtime.h>

typedef float f32x4 __attribute__((ext_vector_type(4)));
typedef __bf16 bf16x8 __attribute__((ext_vector_type(8)));

#define L_SEQ 577
#define BB 8
#define CC 1024
#define HH 16
#define ROWS (L_SEQ*BB)   /* 4616 */

static __device__ __forceinline__ ushort f2b(float f) {
  unsigned u = __float_as_uint(f);
  u += 0x7fffu + ((u >> 16) & 1u);
  return (ushort)(u >> 16);
}

static __device__ __forceinline__ void gld16(const void* g, void* l) {
  __builtin_amdgcn_global_load_lds((const __attribute__((address_space(1))) void*)g,
                                   (__attribute__((address_space(3))) void*)l, 16, 0, 0);
}

// ---------------- fp32 -> bf16 convert ----------------
__global__ void cvt_kernel(const float* __restrict__ src, ushort* __restrict__ dst, int n4) {
  int i = blockIdx.x * blockDim.x + threadIdx.x;
  if (i < n4) {
    float4 v = *(const float4*)(src + (size_t)i * 4);
    ushort4 o;
    o.x = f2b(v.x); o.y = f2b(v.y); o.z = f2b(v.z); o.w = f2b(v.w);
    *(ushort4*)(dst + (size_t)i * 4) = o;
  }
}

// ---------------- LayerNorm: fp32 x -> bf16 h ----------------
__global__ __launch_bounds__(256)
void ln_kernel(const float* __restrict__ x, const float* __restrict__ g,
               const float* __restrict__ be, ushort* __restrict__ out)
{
  const int row = blockIdx.x;
  const int t = threadIdx.x;
  const float* xr = x + (size_t)row * CC;
  float4 v = *(const float4*)(xr + t * 4);
  float s  = v.x + v.y + v.z + v.w;
  float s2 = v.x*v.x + v.y*v.y + v.z*v.z + v.w*v.w;
  #pragma unroll
  for (int sd = 1; sd < 64; sd <<= 1) { s += __shfl_xor(s, sd, 64); s2 += __shfl_xor(s2, sd, 64); }
  __shared__ float ps[4], ps2[4];
  const int w = t >> 6;
  if ((t & 63) == 0) { ps[w] = s; ps2[w] = s2; }
  __syncthreads();
  s  = ps[0] + ps[1] + ps[2] + ps[3];
  s2 = ps2[0] + ps2[1] + ps2[2] + ps2[3];
  const float mean = s * (1.f / 1024.f);
  const float var  = s2 * (1.f / 1024.f) - mean * mean;
  const float rstd = rsqrtf(var + 1e-5f);
  float4 gv = *(const float4*)(g + t * 4);
  float4 bv = *(const float4*)(be + t * 4);
  ushort4 o;
  o.x = f2b((v.x - mean) * rstd * gv.x + bv.x);
  o.y = f2b((v.y - mean) * rstd * gv.y + bv.y);
  o.z = f2b((v.z - mean) * rstd * gv.z + bv.z);
  o.w = f2b((v.w - mean) * rstd * gv.w + bv.w);
  *(ushort4*)(out + (size_t)row * CC + t * 4) = o;
}

// ---------------- V transpose: qkv v-part -> vt[b][n][m] ----------------
__global__ __launch_bounds__(256)
void vt_kernel(const ushort* __restrict__ qkv, ushort* __restrict__ vt)
{
  __shared__ ushort tile[32][33];
  const int lt = blockIdx.x * 32;   // l tile (0..18 -> 608)
  const int nt = blockIdx.y * 32;   // n tile (0..31 -> 1024)
  const int b  = blockIdx.z;
  const int tx = threadIdx.x & 31;
  const int ty = threadIdx.x >> 5;  // 0..7
  #pragma unroll
  for (int p = 0; p < 4; ++p) {
    int l = lt + ty + p * 8;
    ushort v = 0;
    if (l < L_SEQ) v = qkv[((size_t)l * BB + b) * 3072 + 2048 + nt + tx];
    tile[ty + p * 8][tx] = v;
  }
  __syncthreads();
  #pragma unroll
  for (int p = 0; p < 4; ++p) {
    int n = nt + ty + p * 8;
    int l = lt + tx;
    vt[((size_t)b * 1024 + n) * 608 + l] = tile[tx][ty + p * 8];
  }
}

// ---------------- attention: scores+softmax+head-avg -> bf16 attn [8][608][608] ----------------
__global__ __launch_bounds__(256, 2)
void attn_kernel(const ushort* __restrict__ qkv,
                 const float* __restrict__ bias,   // layer base [B*H,577,577]
                 ushort* __restrict__ attn)
{
  __shared__ float S[2][16][600];
  const int t = threadIdx.x;
  const int lane = t & 63;
  const int w = t >> 6;
  const int rb = blockIdx.x;       // 0..36
  const int b  = blockIdx.y;       // 0..7
  const int r0 = rb * 16;
  float acc[37];
  #pragma unroll
  for (int k = 0; k < 37; ++k) acc[k] = 0.f;

  const int fr = lane & 15;
  const int kc = (lane >> 4) * 8;
  const int arow = min(r0 + fr, L_SEQ - 1);
  const size_t abase = ((size_t)arow * BB + b) * 3072;

  for (int h = 0; h < HH; ++h) {
    const int qoff = h * 64;
    const int koff = CC + h * 64;
    bf16x8 aq0 = *(const bf16x8*)(qkv + abase + qoff + kc);
    bf16x8 aq1 = *(const bf16x8*)(qkv + abase + qoff + 32 + kc);
    bf16x8 ak0 = *(const bf16x8*)(qkv + abase + koff + kc);
    bf16x8 ak1 = *(const bf16x8*)(qkv + abase + koff + 32 + kc);
    for (int nt = w; nt < 37; nt += 4) {
      const int col = nt * 16 + fr;
      const int ncl = min(col, L_SEQ - 1);
      const size_t brow = ((size_t)ncl * BB + b) * 3072;
      bf16x8 bq0 = *(const bf16x8*)(qkv + brow + qoff + kc);
      bf16x8 bq1 = *(const bf16x8*)(qkv + brow + qoff + 32 + kc);
      bf16x8 bk0 = *(const bf16x8*)(qkv + brow + koff + kc);
      bf16x8 bk1 = *(const bf16x8*)(qkv + brow + koff + 32 + kc);
      f32x4 dq = {0.f, 0.f, 0.f, 0.f};
      f32x4 dk = {0.f, 0.f, 0.f, 0.f};
      dq = __builtin_amdgcn_mfma_f32_16x16x32_bf16(aq0, bq0, dq, 0, 0, 0);
      dq = __builtin_amdgcn_mfma_f32_16x16x32_bf16(aq1, bq1, dq, 0, 0, 0);
      dk = __builtin_amdgcn_mfma_f32_16x16x32_bf16(ak0, bk0, dk, 0, 0, 0);
      dk = __builtin_amdgcn_mfma_f32_16x16x32_bf16(ak1, bk1, dk, 0, 0, 0);
      const bool cvalid = (col < L_SEQ);
      #pragma unroll
      for (int r = 0; r < 4; ++r) {
        int row = (lane >> 4) * 4 + r;            // tile row 0..15
        int l = min(r0 + row, L_SEQ - 1);
        float bs = bias[(((size_t)(b * HH + h)) * L_SEQ + l) * L_SEQ + min(col, L_SEQ - 1)];
        S[0][row][col] = cvalid ? (bs + 0.125f * dq[r]) : -1e30f;
        S[1][row][col] = cvalid ? (bs + 0.125f * dk[r]) : -1e30f;
      }
    }
    __syncthreads();
    const int rr = t >> 4;
    const int j0 = t & 15;
    #pragma unroll
    for (int v = 0; v < 2; ++v) {
      float mx = -1e30f;
      #pragma unroll
      for (int k = 0; k < 37; ++k) mx = fmaxf(mx, S[v][rr][j0 + 16 * k]);
      #pragma unroll
      for (int sd = 1; sd < 16; sd <<= 1) mx = fmaxf(mx, __shfl_xor(mx, sd, 16));
      float e[37]; float sm = 0.f;
      #pragma unroll
      for (int k = 0; k < 37; ++k) { e[k] = __expf(S[v][rr][j0 + 16 * k] - mx); sm += e[k]; }
      #pragma unroll
      for (int sd = 1; sd < 16; sd <<= 1) sm += __shfl_xor(sm, sd, 16);
      float inv = 0.03125f / sm;   // 1/(2H) / sum
      #pragma unroll
      for (int k = 0; k < 37; ++k) acc[k] += e[k] * inv;
    }
    __syncthreads();
  }
  const int rr = t >> 4;
  const int j0 = t & 15;
  const int l = r0 + rr;
  if (l < L_SEQ) {
    ushort* dst = attn + (size_t)b * 608 * 608 + (size_t)l * 608;
    #pragma unroll
    for (int k = 0; k < 37; ++k) dst[j0 + 16 * k] = f2b(acc[k]);
  }
}

// ---------------- generic bf16 GEMM: C = A[M,K] * B[N,K]^T, fused epilogues ----------------
// EPI: 0=QKV(bf16,+bias) 1=GELU(bf16,+bias) 2=RESID(fp32 x+=D+bias) 3=ATTNV(bf16, row->row*8+bz)
template<int EPI>
__global__ __launch_bounds__(256, 2)
void gemm_bt(const ushort* __restrict__ A, int lda, int Arows, long aStride,
             const ushort* __restrict__ B, int ldb, long bStride,
             int M, int N, int K,
             const float* __restrict__ bias,
             float* __restrict__ xio,
             ushort* __restrict__ outb, int ldo)
{
  __shared__ __align__(16) ushort As[128 * 32];
  __shared__ __align__(16) ushort Bs[128 * 32];
  const int t = threadIdx.x;
  const int lane = t & 63;
  const int w = t >> 6;
  const int bm = blockIdx.x, bn = blockIdx.y, bz = blockIdx.z;
  const ushort* Ab = A + (long)bz * aStride;
  const ushort* Bb = B + (long)bz * bStride;
  const int srow = t >> 2;
  const int sc = (t & 3) * 8;
  const int wr = (w >> 1) * 64;
  const int wc = (w & 1) * 64;
  const int am1 = Arows - 1;
  f32x4 acc[4][4] = {};

  const int r0a = bm * 128 + srow;
  const int r0b = bn * 128 + srow;
  for (int kt = 0; kt < K; kt += 32) {
    __syncthreads();
    gld16(Ab + (size_t)min(r0a, am1) * lda + kt + sc, (void*)(As + t * 8));
    gld16(Ab + (size_t)min(r0a + 64, am1) * lda + kt + sc, (void*)(As + 2048 + t * 8));
    gld16(Bb + (size_t)r0b * ldb + kt + sc, (void*)(Bs + t * 8));
    gld16(Bb + (size_t)(r0b + 64) * ldb + kt + sc, (void*)(Bs + 2048 + t * 8));
    asm volatile("s_waitcnt vmcnt(0)" ::: "memory");
    __syncthreads();
    bf16x8 av[4], bv[4];
    const int fr = lane & 15;
    const int kc = (lane >> 4) * 8;
    #pragma unroll
    for (int m = 0; m < 4; ++m) av[m] = *(const bf16x8*)(As + (wr + m * 16 + fr) * 32 + kc);
    #pragma unroll
    for (int n = 0; n < 4; ++n) bv[n] = *(const bf16x8*)(Bs + (wc + n * 16 + fr) * 32 + kc);
    #pragma unroll
    for (int m = 0; m < 4; ++m)
      #pragma unroll
      for (int n = 0; n < 4; ++n)
        acc[m][n] = __builtin_amdgcn_mfma_f32_16x16x32_bf16(av[m], bv[n], acc[m][n], 0, 0, 0);
  }
  const int rbase = wr + (lane >> 4) * 4;
  const int cbase = wc + (lane & 15);
  #pragma unroll
  for (int n = 0; n < 4; ++n) {
    const int gn = bn * 128 + cbase + n * 16;
    const float bval = (EPI == 3) ? 0.f : bias[gn];
    #pragma unroll
    for (int m = 0; m < 4; ++m) {
      f32x4 d = acc[m][n];
      #pragma unroll
      for (int r = 0; r < 4; ++r) {
        const int gm = bm * 128 + rbase + m * 16 + r;
        if (gm < M) {
          if (EPI == 0) {
            outb[(size_t)gm * ldo + gn] = f2b(d[r] + bval);
          } else if (EPI == 1) {
            float v0 = d[r] + bval;
            outb[(size_t)gm * ldo + gn] = f2b(v0 / (1.f + __expf(-1.702f * v0)));
          } else if (EPI == 2) {
            xio[(size_t)gm * ldo + gn] += d[r] + bval;
          } else {
            outb[((size_t)gm * 8 + bz) * ldo + gn] = f2b(d[r]);
          }
        }
      }
    }
  }
}

extern "C" void kernel_launch(void* const* d_in, const int* in_sizes, int n_in,
                              void* d_out, int out_size, void* d_ws, size_t ws_size,
                              hipStream_t stream)
{
  (void)in_sizes; (void)n_in; (void)out_size; (void)ws_size;
  const float* x_in  = (const float*)d_in[0];
  const float* attb  = (const float*)d_in[1];
  const float* ln1_g = (const float*)d_in[2];
  const float* ln1_b = (const float*)d_in[3];
  const float* in_w  = (const float*)d_in[4];
  const float* in_b  = (const float*)d_in[5];
  const float* out_w = (const float*)d_in[6];
  const float* out_b = (const float*)d_in[7];
  const float* ln2_g = (const float*)d_in[8];
  const float* ln2_b = (const float*)d_in[9];
  const float* fc1_w = (const float*)d_in[10];
  const float* fc1_b = (const float*)d_in[11];
  const float* fc2_w = (const float*)d_in[12];
  const float* fc2_b = (const float*)d_in[13];
  float* x = (float*)d_out;   // running residual lives in d_out

  char* ws = (char*)d_ws;
  size_t off = 0;
  auto alloc = [&](size_t bytes) -> void* {
    void* p = ws + off; off += (bytes + 255) & ~(size_t)255; return p;
  };
  ushort* wIn   = (ushort*)alloc(2ull * 3072 * 1024 * 2);
  ushort* wOut  = (ushort*)alloc(2ull * 1024 * 1024 * 2);
  ushort* wF1   = (ushort*)alloc(2ull * 4096 * 1024 * 2);
  ushort* wF2   = (ushort*)alloc(2ull * 4096 * 1024 * 2);
  ushort* hbuf  = (ushort*)alloc((size_t)ROWS * 1024 * 2);
  ushort* qkv   = (ushort*)alloc((size_t)ROWS * 3072 * 2);
  ushort* vt    = (ushort*)alloc((size_t)8 * 1024 * 608 * 2);
  ushort* attn  = (ushort*)alloc((size_t)8 * 608 * 608 * 2);
  ushort* outlb = (ushort*)alloc((size_t)ROWS * 1024 * 2);
  ushort* ubuf  = qkv;  // aliases [qkv .. qkv+vt) = 38.3MB >= 37.8MB needed; qkv/vt dead by MLP

  cvt_kernel<<<2 * 3072 * 1024 / 4 / 256, 256, 0, stream>>>(in_w,  wIn,  2 * 3072 * 1024 / 4);
  cvt_kernel<<<2 * 1024 * 1024 / 4 / 256, 256, 0, stream>>>(out_w, wOut, 2 * 1024 * 1024 / 4);
  cvt_kernel<<<2 * 4096 * 1024 / 4 / 256, 256, 0, stream>>>(fc1_w, wF1,  2 * 4096 * 1024 / 4);
  cvt_kernel<<<2 * 4096 * 1024 / 4 / 256, 256, 0, stream>>>(fc2_w, wF2,  2 * 4096 * 1024 / 4);
  hipMemcpyAsync(x, x_in, (size_t)ROWS * 1024 * 4, hipMemcpyDeviceToDevice, stream);

  for (int i = 0; i < 2; ++i) {
    ln_kernel<<<ROWS, 256, 0, stream>>>(x, ln1_g + i * 1024, ln1_b + i * 1024, hbuf);
    gemm_bt<0><<<dim3(37, 24, 1), 256, 0, stream>>>(hbuf, 1024, ROWS, 0,
        wIn + (size_t)i * 3072 * 1024, 1024, 0,
        ROWS, 3072, 1024, in_b + i * 3072, nullptr, qkv, 3072);
    attn_kernel<<<dim3(37, 8, 1), 256, 0, stream>>>(qkv, attb + (size_t)i * 128 * 577 * 577, attn);
    vt_kernel<<<dim3(19, 32, 8), 256, 0, stream>>>(qkv, vt);
    gemm_bt<3><<<dim3(5, 8, 8), 256, 0, stream>>>(attn, 608, 577, (long)608 * 608,
        vt, 608, (long)1024 * 608,
        577, 1024, 608, nullptr, nullptr, outlb, 1024);
    gemm_bt<2><<<dim3(37, 8, 1), 256, 0, stream>>>(outlb, 1024, ROWS, 0,
        wOut + (size_t)i * 1024 * 1024, 1024, 0,
        ROWS, 1024, 1024, out_b + i * 1024, x, nullptr, 1024);
    ln_kernel<<<ROWS, 256, 0, stream>>>(x, ln2_g + i * 1024, ln2_b + i * 1024, hbuf);
    gemm_bt<1><<<dim3(37, 32, 1), 256, 0, stream>>>(hbuf, 1024, ROWS, 0,
        wF1 + (size_t)i * 4096 * 1024, 1024, 0,
        ROWS, 4096, 1024, fc1_b + i * 4096, nullptr, ubuf, 4096);
    gemm_bt<2><<<dim3(37, 8, 1), 256, 0, stream>>>(ubuf, 4096, ROWS, 0,
        wF2 + (size_t)i * 4096 * 1024, 4096, 0,
        ROWS, 1024, 4096, fc2_b + i * 1024, x, nullptr, 1024);
  }
}